// Round 8
// baseline (145.934 us; speedup 1.0000x reference)
//
#include <hip/hip_runtime.h>
#include <hip/hip_bf16.h>

#define BQ 4
#define SQ 4096
#define DQ 256
#define N3 768
#define KBLK 64
#define NITER (SQ / KBLK)

typedef __attribute__((ext_vector_type(8))) _Float16 f16x8;
typedef __attribute__((ext_vector_type(4))) float f32x4;
typedef __attribute__((ext_vector_type(4))) unsigned int u32x4;

__device__ __forceinline__ short f2h(float f) {
  _Float16 h = (_Float16)f;
  union { _Float16 h; short s; } v; v.h = h;
  return v.s;
}

__device__ __forceinline__ void gload16(const void* g, void* lds) {
  __builtin_amdgcn_global_load_lds(
      (const __attribute__((address_space(1))) unsigned int*)g,
      (__attribute__((address_space(3))) unsigned int*)lds, 16, 0, 0);
}

// ---------------- Wcomb = Wproj @ Wfc ; c0 = bproj @ Wfc + bfc ----------------
__global__ void wcomb_kernel(const float* __restrict__ Wproj,
                             const float* __restrict__ bproj,
                             const float* __restrict__ Wfc,
                             const float* __restrict__ bfc,
                             float* __restrict__ Wc) {
  __shared__ float wf[256];
  const int t = threadIdx.x;
  wf[t] = Wfc[t];
  __syncthreads();
  float acc = 0.f;
  for (int j = 0; j < 256; ++j) acc += Wproj[(size_t)t * 256 + j] * wf[j];
  Wc[t] = acc;
  if (t == 0) {
    float c = bfc[0];
    for (int j = 0; j < 256; ++j) c += bproj[j] * wf[j];
    Wc[256] = c;
  }
}

// ---------------- QKV projection (x staged once; u finished in-block) ------
// grid 256 (M-tiles). Per block: stage x[64][256] fp16 once, loop 12 N-tiles.
// N-tiles 0..7 -> Q,K fp16 row-major; 8..11 -> u[row] += (v+bias).Wc  (f32).
__global__ __launch_bounds__(256, 2) void qkv_kernel(
    const float* __restrict__ x, const float* __restrict__ Wqkv,
    const float* __restrict__ bqkv, const float* __restrict__ Wc,
    short* __restrict__ Qb, short* __restrict__ Kb, float* __restrict__ u) {
  __shared__ short xs[64][264];  // [m][k], pitch 528B (33*16B)
  __shared__ short ws[64][264];  // [n][k]
  const int t = threadIdx.x;
  const int l = t & 63, w = t >> 6;
  const int lr = l & 15, lg = l >> 4;
  const int Mbase = blockIdx.x * 64;

  // stage x tile once (each thread: 64 consecutive f32 -> fp16)
  {
    const int m = t >> 2, kc = (t & 3) * 64;
    const float* src = x + (size_t)(Mbase + m) * DQ + kc;
#pragma unroll
    for (int c = 0; c < 4; ++c) {
      short tmp[16];
#pragma unroll
      for (int i = 0; i < 16; ++i) tmp[i] = f2h(src[c * 16 + i]);
      *(u32x4*)&xs[m][kc + c * 16] = *(u32x4*)&tmp[0];
      *(u32x4*)&xs[m][kc + c * 16 + 8] = *(u32x4*)&tmp[8];
    }
  }
  __syncthreads();

  float upart[4] = {0.f, 0.f, 0.f, 0.f};

  for (int nt = 0; nt < 12; ++nt) {
    const int Nbase = nt * 64;
    // stage W^T tile [64 n][256 k] (n over threads -> coalesced)
    {
      const int n = t & 63, kc = (t >> 6) * 64;
#pragma unroll
      for (int c = 0; c < 4; ++c) {
        short tmp[16];
#pragma unroll
        for (int i = 0; i < 16; ++i)
          tmp[i] = f2h(Wqkv[(size_t)(kc + c * 16 + i) * N3 + Nbase + n]);
        *(u32x4*)&ws[n][kc + c * 16] = *(u32x4*)&tmp[0];
        *(u32x4*)&ws[n][kc + c * 16 + 8] = *(u32x4*)&tmp[8];
      }
    }
    __syncthreads();

    f32x4 acc[4] = {};
#pragma unroll
    for (int kk = 0; kk < 8; ++kk) {
      f16x8 af = *(f16x8*)&xs[w * 16 + lr][kk * 32 + lg * 8];
#pragma unroll
      for (int nf = 0; nf < 4; ++nf) {
        f16x8 bfr = *(f16x8*)&ws[nf * 16 + lr][kk * 32 + lg * 8];
        acc[nf] = __builtin_amdgcn_mfma_f32_16x16x32_f16(af, bfr, acc[nf], 0, 0, 0);
      }
    }
    __syncthreads();  // done reading ws before next tile overwrites

    if (nt < 8) {
#pragma unroll
      for (int nf = 0; nf < 4; ++nf) {
        const int col = Nbase + nf * 16 + lr;
        const float bias = bqkv[col];
#pragma unroll
        for (int r = 0; r < 4; ++r) {
          const int row = Mbase + w * 16 + lg * 4 + r;
          const short sv = f2h(acc[nf][r] + bias);
          if (col < 256) Qb[(size_t)row * DQ + col] = sv;
          else           Kb[(size_t)row * DQ + (col - 256)] = sv;
        }
      }
    } else {
#pragma unroll
      for (int nf = 0; nf < 4; ++nf) {
        const int col = Nbase + nf * 16 + lr;
        const float bias = bqkv[col];
        const float wcv = Wc[col - 512];
#pragma unroll
        for (int r = 0; r < 4; ++r) upart[r] += (acc[nf][r] + bias) * wcv;
      }
    }
  }

  // reduce u partials over the lr axis; lane lr==0 writes final u
#pragma unroll
  for (int mask = 1; mask <= 8; mask <<= 1)
#pragma unroll
    for (int r = 0; r < 4; ++r) upart[r] += __shfl_xor(upart[r], mask, 64);
  if (lr == 0) {
#pragma unroll
    for (int r = 0; r < 4; ++r)
      u[Mbase + w * 16 + lg * 4 + r] = upart[r];
  }
}

// ---------------- Flash attention (QK^T + weighted u-sum) ----------------
// grid 512, 256 threads (4 waves). Block = 32 q-rows; wave w = 16-key quarter.
// SINGLE-buffered K tile (33 KB LDS -> 4 blocks/CU), two-barrier loop:
// stage -> barrier(vmcnt drain) -> compute -> barrier.
__global__ __launch_bounds__(256, 4) void attn_kernel(
    const short* __restrict__ Qb, const short* __restrict__ Kb,
    const float* __restrict__ u, const float* __restrict__ Wc,
    float* __restrict__ out) {
  __shared__ short Ks[64][256];   // [key][d], XOR-swizzled chunks
  __shared__ float Mrg[4][32][3]; // [h][row]{m,den,num}

  const int t = threadIdx.x;
  const int l = t & 63, w = t >> 6;  // w = key-quarter
  const int lr = l & 15, lg = l >> 4;
  const int bid = blockIdx.x;
  const int b = bid & 3;
  const int qbase = (bid >> 2) * 32;

  const short* kbase = Kb + (size_t)b * SQ * DQ;
  const float* ubase = u + (size_t)b * SQ;

  // Q fragments (B-operand): qrow = mm*16+lr, d = kk*32 + lg*8 + j
  f16x8 qf[2][8];
#pragma unroll
  for (int mm = 0; mm < 2; ++mm) {
    const short* qptr = Qb + (size_t)(b * SQ + qbase + mm * 16 + lr) * DQ;
#pragma unroll
    for (int kk = 0; kk < 8; ++kk)
      qf[mm][kk] = *(const f16x8*)(qptr + kk * 32 + lg * 8);
  }

  // K: LDS chunk c of row kr holds global chunk c^(kr&7)  (16B chunks)
#define STAGE(KB)                                                           \
  {                                                                         \
    _Pragma("unroll") for (int i = 0; i < 8; ++i) {                         \
      const int kr = w * 16 + i * 2 + (l >> 5);                             \
      const int gc = (l & 31) ^ (kr & 7);                                   \
      gload16(kbase + (size_t)((KB)*64 + kr) * DQ + gc * 8,                 \
              &Ks[w * 16 + i * 2][0]);                                      \
    }                                                                       \
  }

  float m_run[2] = {-1e30f, -1e30f};
  float num[2] = {0.f, 0.f}, den[2] = {0.f, 0.f};

  for (int kb = 0; kb < NITER; ++kb) {
    STAGE(kb);
    __syncthreads();  // vmcnt drained -> tile visible to all waves

    // u values for this lane's 4 keys (same for both mm)
    const f32x4 uv = *(const f32x4*)(ubase + kb * 64 + w * 16 + lg * 4);

    // S^T = K Q^T on this wave's 16 keys (4 independent MFMA chains)
    const char* kR = (const char*)&Ks[w * 16 + lr][0];
    f32x4 sA[2] = {}, sB[2] = {};
#pragma unroll
    for (int kk = 0; kk < 4; ++kk) {
      f16x8 kf = *(const f16x8*)(kR + (((4 * kk + lg) ^ (lr & 7)) << 4));
      sA[0] = __builtin_amdgcn_mfma_f32_16x16x32_f16(kf, qf[0][kk], sA[0], 0, 0, 0);
      sA[1] = __builtin_amdgcn_mfma_f32_16x16x32_f16(kf, qf[1][kk], sA[1], 0, 0, 0);
    }
#pragma unroll
    for (int kk = 4; kk < 8; ++kk) {
      f16x8 kf = *(const f16x8*)(kR + (((4 * kk + lg) ^ (lr & 7)) << 4));
      sB[0] = __builtin_amdgcn_mfma_f32_16x16x32_f16(kf, qf[0][kk], sB[0], 0, 0, 0);
      sB[1] = __builtin_amdgcn_mfma_f32_16x16x32_f16(kf, qf[1][kk], sB[1], 0, 0, 0);
    }
    f32x4 s[2];
#pragma unroll
    for (int mm = 0; mm < 2; ++mm)
#pragma unroll
      for (int r = 0; r < 4; ++r) s[mm][r] = sA[mm][r] + sB[mm][r];

    // defer-max online softmax; common path has zero cross-lane ops
    bool over = false;
#pragma unroll
    for (int mm = 0; mm < 2; ++mm)
#pragma unroll
      for (int r = 0; r < 4; ++r) over = over || (s[mm][r] > m_run[mm] + 8.f);
    if (__any(over)) {
#pragma unroll
      for (int mm = 0; mm < 2; ++mm) {
        float mt = fmaxf(fmaxf(s[mm][0], s[mm][1]), fmaxf(s[mm][2], s[mm][3]));
        mt = fmaxf(mt, __shfl_xor(mt, 16, 64));
        mt = fmaxf(mt, __shfl_xor(mt, 32, 64));
        const float mn = fmaxf(m_run[mm], mt);
        const float sc = __expf(m_run[mm] - mn);
        m_run[mm] = mn;
        num[mm] *= sc;
        den[mm] *= sc;
      }
    }
#pragma unroll
    for (int mm = 0; mm < 2; ++mm)
#pragma unroll
      for (int r = 0; r < 4; ++r) {
        const float p = __expf(s[mm][r] - m_run[mm]);  // <= e^8
        den[mm] += p;
        num[mm] += p * uv[r];
      }
    __syncthreads();  // all reads of tile done before next STAGE overwrites
  }

  // reduce per-lane partials over the lg axis (keys)
#pragma unroll
  for (int mm = 0; mm < 2; ++mm) {
    num[mm] += __shfl_xor(num[mm], 16, 64);
    num[mm] += __shfl_xor(num[mm], 32, 64);
    den[mm] += __shfl_xor(den[mm], 16, 64);
    den[mm] += __shfl_xor(den[mm], 32, 64);
  }
  if (lg == 0) {
#pragma unroll
    for (int mm = 0; mm < 2; ++mm) {
      Mrg[w][mm * 16 + lr][0] = m_run[mm];
      Mrg[w][mm * 16 + lr][1] = den[mm];
      Mrg[w][mm * 16 + lr][2] = num[mm];
    }
  }
  __syncthreads();

  if (t < 32) {
    float M = Mrg[0][t][0];
#pragma unroll
    for (int hh = 1; hh < 4; ++hh) M = fmaxf(M, Mrg[hh][t][0]);
    float dt = 0.f, nt = 0.f;
#pragma unroll
    for (int hh = 0; hh < 4; ++hh) {
      const float e = __expf(Mrg[hh][t][0] - M);
      dt += e * Mrg[hh][t][1];
      nt += e * Mrg[hh][t][2];
    }
    out[(size_t)b * SQ + qbase + t] = nt / dt + Wc[256];
  }
#undef STAGE
}

// ---------------- launch ----------------
extern "C" void kernel_launch(void* const* d_in, const int* in_sizes, int n_in,
                              void* d_out, int out_size, void* d_ws, size_t ws_size,
                              hipStream_t stream) {
  const float* x     = (const float*)d_in[0];
  const float* Wqkv  = (const float*)d_in[1];
  const float* bqkv  = (const float*)d_in[2];
  const float* Wproj = (const float*)d_in[3];
  const float* bproj = (const float*)d_in[4];
  const float* Wfc   = (const float*)d_in[5];
  const float* bfc   = (const float*)d_in[6];
  float* out = (float*)d_out;

  const size_t SEG = (size_t)BQ * SQ * DQ * 2;  // 8 MB per fp16 tensor
  char* wsb = (char*)d_ws;
  short* Qb = (short*)(wsb);
  short* Kb = (short*)(wsb + SEG);
  float* Wc = (float*)(wsb + 2 * SEG);           // 257 floats
  float* u  = (float*)(wsb + 2 * SEG + 4096);    // 16384 floats

  wcomb_kernel<<<1, 256, 0, stream>>>(Wproj, bproj, Wfc, bfc, Wc);
  qkv_kernel<<<256, 256, 0, stream>>>(x, Wqkv, bqkv, Wc, Qb, Kb, u);
  attn_kernel<<<512, 256, 0, stream>>>(Qb, Kb, u, Wc, out);
}

// Round 9
// 144.888 us; speedup vs baseline: 1.0072x; 1.0072x over previous
//
#include <hip/hip_runtime.h>
#include <hip/hip_bf16.h>

#define BQ 4
#define SQ 4096
#define DQ 256
#define N3 768
#define KBLK 64
#define NITER (SQ / KBLK)
#define KHALF (NITER / 2)

typedef __attribute__((ext_vector_type(8))) _Float16 f16x8;
typedef __attribute__((ext_vector_type(4))) float f32x4;
typedef __attribute__((ext_vector_type(4))) unsigned int u32x4;

__device__ __forceinline__ short f2h(float f) {
  _Float16 h = (_Float16)f;
  union { _Float16 h; short s; } v; v.h = h;
  return v.s;
}

__device__ __forceinline__ void gload16(const void* g, void* lds) {
  __builtin_amdgcn_global_load_lds(
      (const __attribute__((address_space(1))) unsigned int*)g,
      (__attribute__((address_space(3))) unsigned int*)lds, 16, 0, 0);
}

// ---------------- Wcomb = Wproj @ Wfc ; c0 = bproj @ Wfc + bfc ----------------
__global__ void wcomb_kernel(const float* __restrict__ Wproj,
                             const float* __restrict__ bproj,
                             const float* __restrict__ Wfc,
                             const float* __restrict__ bfc,
                             float* __restrict__ Wc) {
  __shared__ float wf[256];
  const int t = threadIdx.x;
  wf[t] = Wfc[t];
  __syncthreads();
  float acc = 0.f;
  for (int j = 0; j < 256; ++j) acc += Wproj[(size_t)t * 256 + j] * wf[j];
  Wc[t] = acc;
  if (t == 0) {
    float c = bfc[0];
    for (int j = 0; j < 256; ++j) c += bproj[j] * wf[j];
    Wc[256] = c;
  }
}

// ---------------- W16T[n][k] = fp16(Wqkv[k][n]) : 768 x 256 ----------------
__global__ void wconv_kernel(const float* __restrict__ Wqkv,
                             short* __restrict__ W16T) {
  const int n = blockIdx.x, k = threadIdx.x;
  W16T[(size_t)n * 256 + k] = f2h(Wqkv[(size_t)k * N3 + n]);
}

// ---------------- QKV projection ----------------
// grid 256 (64-row M-tiles), 1024 threads (16 waves). x staged once (fp16);
// per N-tile: W16T tile staged via global_load_lds (XOR-swizzled), MFMA.
// N-tiles 0..7 -> Q,K; 8..11 -> u[row] += (v+bias).Wc  (f32).
__global__ __launch_bounds__(1024) void qkv_kernel(
    const float* __restrict__ x, const short* __restrict__ W16T,
    const float* __restrict__ bqkv, const float* __restrict__ Wc,
    short* __restrict__ Qb, short* __restrict__ Kb, float* __restrict__ u) {
  __shared__ short xs[64][264];     // [m][k] fp16, pitch 528B
  __shared__ short ws[64][256];     // [n][k] fp16 linear, XOR-swizzled chunks
  __shared__ float u_red[4][4][16]; // [mq][nq][row16]
  const int t = threadIdx.x;
  const int l = t & 63, w = t >> 6;
  const int lr = l & 15, lg = l >> 4;
  const int mq = w >> 2, nq = w & 3;
  const int Mbase = blockIdx.x * 64;

  // stage x tile once (each thread: 16 consecutive f32 -> fp16)
  {
    const int m = t >> 4, kc = (t & 15) * 16;
    const float* src = x + (size_t)(Mbase + m) * DQ + kc;
    short tmp[16];
#pragma unroll
    for (int i = 0; i < 16; ++i) tmp[i] = f2h(src[i]);
    *(u32x4*)&xs[m][kc] = *(u32x4*)&tmp[0];
    *(u32x4*)&xs[m][kc + 8] = *(u32x4*)&tmp[8];
  }

  float upart[4] = {0.f, 0.f, 0.f, 0.f};

  for (int nt = 0; nt < 12; ++nt) {
    const int Nbase = nt * 64;
    // stage W16T tile [64 n][256 k]: wave w fills rows w*4 .. w*4+3
#pragma unroll
    for (int i = 0; i < 2; ++i) {
      const int n = w * 4 + i * 2 + (l >> 5);
      const int gc = (l & 31) ^ (n & 7);
      gload16(W16T + (size_t)(Nbase + n) * 256 + gc * 8, &ws[w * 4 + i * 2][0]);
    }
    __syncthreads();  // vmcnt drained (+ xs ready on nt==0)

    f32x4 acc = {};
    const char* wR = (const char*)&ws[nq * 16 + lr][0];
#pragma unroll
    for (int kk = 0; kk < 8; ++kk) {
      f16x8 af = *(f16x8*)&xs[mq * 16 + lr][kk * 32 + lg * 8];
      f16x8 bfr = *(const f16x8*)(wR + (((4 * kk + lg) ^ (lr & 7)) << 4));
      acc = __builtin_amdgcn_mfma_f32_16x16x32_f16(af, bfr, acc, 0, 0, 0);
    }

    if (nt < 8) {
      const int col = Nbase + nq * 16 + lr;
      const float bias = bqkv[col];
#pragma unroll
      for (int r = 0; r < 4; ++r) {
        const int row = Mbase + mq * 16 + lg * 4 + r;
        const short sv = f2h(acc[r] + bias);
        if (col < 256) Qb[(size_t)row * DQ + col] = sv;
        else           Kb[(size_t)row * DQ + (col - 256)] = sv;
      }
    } else {
      const int col = Nbase + nq * 16 + lr;
      const float bias = bqkv[col];
      const float wcv = Wc[col - 512];
#pragma unroll
      for (int r = 0; r < 4; ++r) upart[r] += (acc[r] + bias) * wcv;
    }
    __syncthreads();  // reads of ws done before next stage overwrites
  }

  // reduce u partials over lr lanes, then over nq waves
#pragma unroll
  for (int mask = 1; mask <= 8; mask <<= 1)
#pragma unroll
    for (int r = 0; r < 4; ++r) upart[r] += __shfl_xor(upart[r], mask, 64);
  if (lr == 0) {
#pragma unroll
    for (int r = 0; r < 4; ++r) u_red[mq][nq][lg * 4 + r] = upart[r];
  }
  __syncthreads();
  if (t < 64)
    u[Mbase + t] = u_red[t >> 4][0][t & 15] + u_red[t >> 4][1][t & 15] +
                   u_red[t >> 4][2][t & 15] + u_red[t >> 4][3][t & 15];
}

// ---------------- Flash attention (QK^T + weighted u-sum), key-split x2 ----
// grid 1024 = (b, half, qtile): 4 blocks/CU. 256 thr (4 waves = key quarters).
// Block: 32 q-rows x 2048 keys. Writes per-row partial (m, den, num).
__global__ __launch_bounds__(256, 4) void attn_kernel(
    const short* __restrict__ Qb, const short* __restrict__ Kb,
    const float* __restrict__ u, float* __restrict__ Pm,
    float* __restrict__ Pd, float* __restrict__ Pn) {
  __shared__ short Ks[64][256];   // [key][d], XOR-swizzled chunks
  __shared__ float Mrg[4][32][3]; // [h][row]{m,den,num}

  const int t = threadIdx.x;
  const int l = t & 63, w = t >> 6;  // w = key-quarter
  const int lr = l & 15, lg = l >> 4;
  const int bid = blockIdx.x;
  const int b = bid & 3;
  const int half = (bid >> 2) & 1;
  const int qbase = (bid >> 3) * 32;

  const short* kbase = Kb + (size_t)b * SQ * DQ;
  const float* ubase = u + (size_t)b * SQ;

  // Q fragments (B-operand): qrow = mm*16+lr, d = kk*32 + lg*8 + j
  f16x8 qf[2][8];
#pragma unroll
  for (int mm = 0; mm < 2; ++mm) {
    const short* qptr = Qb + (size_t)(b * SQ + qbase + mm * 16 + lr) * DQ;
#pragma unroll
    for (int kk = 0; kk < 8; ++kk)
      qf[mm][kk] = *(const f16x8*)(qptr + kk * 32 + lg * 8);
  }

#define STAGE(KB)                                                           \
  {                                                                         \
    _Pragma("unroll") for (int i = 0; i < 8; ++i) {                         \
      const int kr = w * 16 + i * 2 + (l >> 5);                             \
      const int gc = (l & 31) ^ (kr & 7);                                   \
      gload16(kbase + (size_t)((KB)*64 + kr) * DQ + gc * 8,                 \
              &Ks[w * 16 + i * 2][0]);                                      \
    }                                                                       \
  }

  float m_run[2] = {-1e30f, -1e30f};
  float num[2] = {0.f, 0.f}, den[2] = {0.f, 0.f};

  for (int kb = 0; kb < KHALF; ++kb) {
    const int kt = half * KHALF + kb;
    STAGE(kt);
    __syncthreads();  // vmcnt drained -> tile visible

    const f32x4 uv = *(const f32x4*)(ubase + kt * 64 + w * 16 + lg * 4);

    // S^T = K Q^T on this wave's 16 keys
    const char* kR = (const char*)&Ks[w * 16 + lr][0];
    f32x4 sA[2] = {}, sB[2] = {};
    __builtin_amdgcn_s_setprio(1);
#pragma unroll
    for (int kk = 0; kk < 4; ++kk) {
      f16x8 kf = *(const f16x8*)(kR + (((4 * kk + lg) ^ (lr & 7)) << 4));
      sA[0] = __builtin_amdgcn_mfma_f32_16x16x32_f16(kf, qf[0][kk], sA[0], 0, 0, 0);
      sA[1] = __builtin_amdgcn_mfma_f32_16x16x32_f16(kf, qf[1][kk], sA[1], 0, 0, 0);
    }
#pragma unroll
    for (int kk = 4; kk < 8; ++kk) {
      f16x8 kf = *(const f16x8*)(kR + (((4 * kk + lg) ^ (lr & 7)) << 4));
      sB[0] = __builtin_amdgcn_mfma_f32_16x16x32_f16(kf, qf[0][kk], sB[0], 0, 0, 0);
      sB[1] = __builtin_amdgcn_mfma_f32_16x16x32_f16(kf, qf[1][kk], sB[1], 0, 0, 0);
    }
    __builtin_amdgcn_s_setprio(0);
    f32x4 s[2];
#pragma unroll
    for (int mm = 0; mm < 2; ++mm)
#pragma unroll
      for (int r = 0; r < 4; ++r) s[mm][r] = sA[mm][r] + sB[mm][r];

    // defer-max online softmax; zero cross-lane ops in common path
    bool over = false;
#pragma unroll
    for (int mm = 0; mm < 2; ++mm)
#pragma unroll
      for (int r = 0; r < 4; ++r) over = over || (s[mm][r] > m_run[mm] + 8.f);
    if (__any(over)) {
#pragma unroll
      for (int mm = 0; mm < 2; ++mm) {
        float mt = fmaxf(fmaxf(s[mm][0], s[mm][1]), fmaxf(s[mm][2], s[mm][3]));
        mt = fmaxf(mt, __shfl_xor(mt, 16, 64));
        mt = fmaxf(mt, __shfl_xor(mt, 32, 64));
        const float mn = fmaxf(m_run[mm], mt);
        const float sc = __expf(m_run[mm] - mn);
        m_run[mm] = mn;
        num[mm] *= sc;
        den[mm] *= sc;
      }
    }
#pragma unroll
    for (int mm = 0; mm < 2; ++mm)
#pragma unroll
      for (int r = 0; r < 4; ++r) {
        const float p = __expf(s[mm][r] - m_run[mm]);  // <= e^8
        den[mm] += p;
        num[mm] += p * uv[r];
      }
    __syncthreads();  // reads done before next STAGE overwrites
  }

  // reduce per-lane partials over the lg axis (keys)
#pragma unroll
  for (int mm = 0; mm < 2; ++mm) {
    num[mm] += __shfl_xor(num[mm], 16, 64);
    num[mm] += __shfl_xor(num[mm], 32, 64);
    den[mm] += __shfl_xor(den[mm], 16, 64);
    den[mm] += __shfl_xor(den[mm], 32, 64);
  }
  if (lg == 0) {
#pragma unroll
    for (int mm = 0; mm < 2; ++mm) {
      Mrg[w][mm * 16 + lr][0] = m_run[mm];
      Mrg[w][mm * 16 + lr][1] = den[mm];
      Mrg[w][mm * 16 + lr][2] = num[mm];
    }
  }
  __syncthreads();

  if (t < 32) {
    float M = Mrg[0][t][0];
#pragma unroll
    for (int hh = 1; hh < 4; ++hh) M = fmaxf(M, Mrg[hh][t][0]);
    float dt = 0.f, nt = 0.f;
#pragma unroll
    for (int hh = 0; hh < 4; ++hh) {
      const float e = __expf(Mrg[hh][t][0] - M);
      dt += e * Mrg[hh][t][1];
      nt += e * Mrg[hh][t][2];
    }
    const size_t idx = (size_t)half * (BQ * SQ) + (size_t)b * SQ + qbase + t;
    Pm[idx] = M; Pd[idx] = dt; Pn[idx] = nt;
  }
#undef STAGE
}

// ---------------- merge the 2 key-halves ----------------
__global__ void merge_kernel(const float* __restrict__ Pm,
                             const float* __restrict__ Pd,
                             const float* __restrict__ Pn,
                             const float* __restrict__ Wc,
                             float* __restrict__ out) {
  const int gid = blockIdx.x * 256 + threadIdx.x;
  const float m0 = Pm[gid], m1 = Pm[BQ * SQ + gid];
  const float M = fmaxf(m0, m1);
  const float e0 = __expf(m0 - M), e1 = __expf(m1 - M);
  const float den = e0 * Pd[gid] + e1 * Pd[BQ * SQ + gid];
  const float num = e0 * Pn[gid] + e1 * Pn[BQ * SQ + gid];
  out[gid] = num / den + Wc[256];
}

// ---------------- launch ----------------
extern "C" void kernel_launch(void* const* d_in, const int* in_sizes, int n_in,
                              void* d_out, int out_size, void* d_ws, size_t ws_size,
                              hipStream_t stream) {
  const float* x     = (const float*)d_in[0];
  const float* Wqkv  = (const float*)d_in[1];
  const float* bqkv  = (const float*)d_in[2];
  const float* Wproj = (const float*)d_in[3];
  const float* bproj = (const float*)d_in[4];
  const float* Wfc   = (const float*)d_in[5];
  const float* bfc   = (const float*)d_in[6];
  float* out = (float*)d_out;

  const size_t SEG = (size_t)BQ * SQ * DQ * 2;  // 8 MB per fp16 tensor
  char* wsb = (char*)d_ws;
  short* Qb   = (short*)(wsb);
  short* Kb   = (short*)(wsb + SEG);
  char* base  = wsb + 2 * SEG;
  float* Wc   = (float*)(base);                    // 257 f
  float* u    = (float*)(base + 4096);             // 16384 f
  short* W16T = (short*)(base + 4096 + 65536);     // 768*256 fp16 = 384KB
  float* Pm   = (float*)(base + 4096 + 65536 + 393216);            // 32768 f
  float* Pd   = Pm + 2 * BQ * SQ;
  float* Pn   = Pd + 2 * BQ * SQ;

  wcomb_kernel<<<1, 256, 0, stream>>>(Wproj, bproj, Wfc, bfc, Wc);
  wconv_kernel<<<N3, 256, 0, stream>>>(Wqkv, W16T);
  qkv_kernel<<<256, 1024, 0, stream>>>(x, W16T, bqkv, Wc, Qb, Kb, u);
  attn_kernel<<<1024, 256, 0, stream>>>(Qb, Kb, u, Pm, Pd, Pn);
  merge_kernel<<<BQ * SQ / 256, 256, 0, stream>>>(Pm, Pd, Pn, Wc, out);
}

// Round 10
// 136.735 us; speedup vs baseline: 1.0673x; 1.0596x over previous
//
#include <hip/hip_runtime.h>
#include <hip/hip_bf16.h>

#define BQ 4
#define SQ 4096
#define DQ 256
#define N3 768
#define KBLK 64
#define NITER (SQ / KBLK)

typedef __attribute__((ext_vector_type(8))) _Float16 f16x8;
typedef __attribute__((ext_vector_type(4))) float f32x4;
typedef __attribute__((ext_vector_type(4))) unsigned int u32x4;

__device__ __forceinline__ short f2h(float f) {
  _Float16 h = (_Float16)f;
  union { _Float16 h; short s; } v; v.h = h;
  return v.s;
}

__device__ __forceinline__ void gload16(const void* g, void* lds) {
  __builtin_amdgcn_global_load_lds(
      (const __attribute__((address_space(1))) unsigned int*)g,
      (__attribute__((address_space(3))) unsigned int*)lds, 16, 0, 0);
}

// ---------------- Wcomb = Wproj @ Wfc ; c0 = bproj @ Wfc + bfc ----------------
__global__ void wcomb_kernel(const float* __restrict__ Wproj,
                             const float* __restrict__ bproj,
                             const float* __restrict__ Wfc,
                             const float* __restrict__ bfc,
                             float* __restrict__ Wc) {
  __shared__ float wf[256];
  const int t = threadIdx.x;
  wf[t] = Wfc[t];
  __syncthreads();
  float acc = 0.f;
  for (int j = 0; j < 256; ++j) acc += Wproj[(size_t)t * 256 + j] * wf[j];
  Wc[t] = acc;
  if (t == 0) {
    float c = bfc[0];
    for (int j = 0; j < 256; ++j) c += bproj[j] * wf[j];
    Wc[256] = c;
  }
}

// ---------------- W16T[n][k] = fp16(Wqkv[k][n]) : 768 x 256 ----------------
__global__ void wconv_kernel(const float* __restrict__ Wqkv,
                             short* __restrict__ W16T) {
  const int n = blockIdx.x, k = threadIdx.x;
  W16T[(size_t)n * 256 + k] = f2h(Wqkv[(size_t)k * N3 + n]);
}

// ---------------- QKV projection (unchanged from r9) ----------------
__global__ __launch_bounds__(1024) void qkv_kernel(
    const float* __restrict__ x, const short* __restrict__ W16T,
    const float* __restrict__ bqkv, const float* __restrict__ Wc,
    short* __restrict__ Qb, short* __restrict__ Kb, float* __restrict__ u) {
  __shared__ short xs[64][264];
  __shared__ short ws[64][256];
  __shared__ float u_red[4][4][16];
  const int t = threadIdx.x;
  const int l = t & 63, w = t >> 6;
  const int lr = l & 15, lg = l >> 4;
  const int mq = w >> 2, nq = w & 3;
  const int Mbase = blockIdx.x * 64;

  {
    const int m = t >> 4, kc = (t & 15) * 16;
    const float* src = x + (size_t)(Mbase + m) * DQ + kc;
    short tmp[16];
#pragma unroll
    for (int i = 0; i < 16; ++i) tmp[i] = f2h(src[i]);
    *(u32x4*)&xs[m][kc] = *(u32x4*)&tmp[0];
    *(u32x4*)&xs[m][kc + 8] = *(u32x4*)&tmp[8];
  }

  float upart[4] = {0.f, 0.f, 0.f, 0.f};

  for (int nt = 0; nt < 12; ++nt) {
    const int Nbase = nt * 64;
#pragma unroll
    for (int i = 0; i < 2; ++i) {
      const int n = w * 4 + i * 2 + (l >> 5);
      const int gc = (l & 31) ^ (n & 7);
      gload16(W16T + (size_t)(Nbase + n) * 256 + gc * 8, &ws[w * 4 + i * 2][0]);
    }
    __syncthreads();

    f32x4 acc = {};
    const char* wR = (const char*)&ws[nq * 16 + lr][0];
#pragma unroll
    for (int kk = 0; kk < 8; ++kk) {
      f16x8 af = *(f16x8*)&xs[mq * 16 + lr][kk * 32 + lg * 8];
      f16x8 bfr = *(const f16x8*)(wR + (((4 * kk + lg) ^ (lr & 7)) << 4));
      acc = __builtin_amdgcn_mfma_f32_16x16x32_f16(af, bfr, acc, 0, 0, 0);
    }

    if (nt < 8) {
      const int col = Nbase + nq * 16 + lr;
      const float bias = bqkv[col];
#pragma unroll
      for (int r = 0; r < 4; ++r) {
        const int row = Mbase + mq * 16 + lg * 4 + r;
        const short sv = f2h(acc[r] + bias);
        if (col < 256) Qb[(size_t)row * DQ + col] = sv;
        else           Kb[(size_t)row * DQ + (col - 256)] = sv;
      }
    } else {
      const int col = Nbase + nq * 16 + lr;
      const float bias = bqkv[col];
      const float wcv = Wc[col - 512];
#pragma unroll
      for (int r = 0; r < 4; ++r) upart[r] += (acc[r] + bias) * wcv;
    }
    __syncthreads();
  }

#pragma unroll
  for (int mask = 1; mask <= 8; mask <<= 1)
#pragma unroll
    for (int r = 0; r < 4; ++r) upart[r] += __shfl_xor(upart[r], mask, 64);
  if (lr == 0) {
#pragma unroll
    for (int r = 0; r < 4; ++r) u_red[mq][nq][lg * 4 + r] = upart[r];
  }
  __syncthreads();
  if (t < 64)
    u[Mbase + t] = u_red[t >> 4][0][t & 15] + u_red[t >> 4][1][t & 15] +
                   u_red[t >> 4][2][t & 15] + u_red[t >> 4][3][t & 15];
}

// ---------------- Flash attention (QK^T + weighted u-sum) ----------------
// grid 256 (1 block/CU), 256 thr (4 waves = 2 q-groups x 2 key-halves).
// Block = 64 q-rows x ALL 4096 keys; wave = 32 q-rows x 32 keys per 64-key
// tile. K tile double-buffered via global_load_lds (XOR-swizzled). In-block
// end merge of the 2 key-halves; direct out write.
__global__ __launch_bounds__(256, 1) void attn_kernel(
    const short* __restrict__ Qb, const short* __restrict__ Kb,
    const float* __restrict__ u, const float* __restrict__ Wc,
    float* __restrict__ out) {
  __shared__ short Ks[2][64][256];   // [buf][key][d], XOR-swizzled chunks
  __shared__ float Mrg[2][2][32][3]; // [qg][h][row]{m,den,num}

  const int t = threadIdx.x;
  const int l = t & 63, w = t >> 6;
  const int lr = l & 15, lg = l >> 4;
  const int qg = w >> 1, h = w & 1;
  const int bid = blockIdx.x;
  const int b = bid & 3;              // bid%8 -> XCD: each XCD serves one b
  const int qbase = (bid >> 2) * 64;

  const short* kbase = Kb + (size_t)b * SQ * DQ;
  const float* ubase = u + (size_t)b * SQ;

  // Q fragments (B-operand): wave's 32 q-rows (qg), qrow = mm*16+lr
  f16x8 qf[2][8];
#pragma unroll
  for (int mm = 0; mm < 2; ++mm) {
    const short* qptr = Qb + (size_t)(b * SQ + qbase + qg * 32 + mm * 16 + lr) * DQ;
#pragma unroll
    for (int kk = 0; kk < 8; ++kk)
      qf[mm][kk] = *(const f16x8*)(qptr + kk * 32 + lg * 8);
  }

  // K: LDS chunk c of row kr holds global chunk c^(kr&7)  (16B chunks)
#define STAGE(BUF, KB)                                                      \
  {                                                                         \
    _Pragma("unroll") for (int i = 0; i < 8; ++i) {                         \
      const int kr = w * 16 + i * 2 + (l >> 5);                             \
      const int gc = (l & 31) ^ (kr & 7);                                   \
      gload16(kbase + (size_t)((KB)*64 + kr) * DQ + gc * 8,                 \
              &Ks[BUF][w * 16 + i * 2][0]);                                 \
    }                                                                       \
  }

  float m_run[2] = {-1e30f, -1e30f};
  float num[2] = {0.f, 0.f}, den[2] = {0.f, 0.f};

  STAGE(0, 0);
  __syncthreads();  // buf0 ready

  for (int kb = 0; kb < NITER; ++kb) {
    const int cur = kb & 1;
    if (kb + 1 < NITER) STAGE(cur ^ 1, kb + 1);

    // S^T = K Q^T on this wave's 32 keys (2 chunks x 2 mm, split chains)
    f32x4 sA[2][2] = {}, sB[2][2] = {};
#pragma unroll
    for (int kc = 0; kc < 2; ++kc) {
      const char* kR = (const char*)&Ks[cur][h * 32 + kc * 16 + lr][0];
#pragma unroll
      for (int kk = 0; kk < 4; ++kk) {
        f16x8 kf = *(const f16x8*)(kR + (((4 * kk + lg) ^ (lr & 7)) << 4));
        sA[kc][0] = __builtin_amdgcn_mfma_f32_16x16x32_f16(kf, qf[0][kk], sA[kc][0], 0, 0, 0);
        sA[kc][1] = __builtin_amdgcn_mfma_f32_16x16x32_f16(kf, qf[1][kk], sA[kc][1], 0, 0, 0);
      }
#pragma unroll
      for (int kk = 4; kk < 8; ++kk) {
        f16x8 kf = *(const f16x8*)(kR + (((4 * kk + lg) ^ (lr & 7)) << 4));
        sB[kc][0] = __builtin_amdgcn_mfma_f32_16x16x32_f16(kf, qf[0][kk], sB[kc][0], 0, 0, 0);
        sB[kc][1] = __builtin_amdgcn_mfma_f32_16x16x32_f16(kf, qf[1][kk], sB[kc][1], 0, 0, 0);
      }
    }
    f32x4 s[2][2];
#pragma unroll
    for (int kc = 0; kc < 2; ++kc)
#pragma unroll
      for (int mm = 0; mm < 2; ++mm)
#pragma unroll
        for (int r = 0; r < 4; ++r) s[kc][mm][r] = sA[kc][mm][r] + sB[kc][mm][r];

    // defer-max online softmax; zero cross-lane ops in common path
    bool over = false;
#pragma unroll
    for (int kc = 0; kc < 2; ++kc)
#pragma unroll
      for (int mm = 0; mm < 2; ++mm)
#pragma unroll
        for (int r = 0; r < 4; ++r) over = over || (s[kc][mm][r] > m_run[mm] + 8.f);
    if (__any(over)) {
#pragma unroll
      for (int mm = 0; mm < 2; ++mm) {
        float mt = s[0][mm][0];
#pragma unroll
        for (int r = 1; r < 4; ++r) mt = fmaxf(mt, s[0][mm][r]);
#pragma unroll
        for (int r = 0; r < 4; ++r) mt = fmaxf(mt, s[1][mm][r]);
        mt = fmaxf(mt, __shfl_xor(mt, 16, 64));
        mt = fmaxf(mt, __shfl_xor(mt, 32, 64));
        const float mn = fmaxf(m_run[mm], mt);
        const float sc = __expf(m_run[mm] - mn);
        m_run[mm] = mn;
        num[mm] *= sc;
        den[mm] *= sc;
      }
    }
#pragma unroll
    for (int kc = 0; kc < 2; ++kc) {
      const f32x4 uv = *(const f32x4*)(ubase + kb * 64 + h * 32 + kc * 16 + lg * 4);
#pragma unroll
      for (int mm = 0; mm < 2; ++mm)
#pragma unroll
        for (int r = 0; r < 4; ++r) {
          const float p = __expf(s[kc][mm][r] - m_run[mm]);  // <= e^8
          den[mm] += p;
          num[mm] += p * uv[r];
        }
    }
    __syncthreads();  // next tile landed + reads of cur done
  }

  // reduce per-lane partials over the lg axis (keys)
#pragma unroll
  for (int mm = 0; mm < 2; ++mm) {
    num[mm] += __shfl_xor(num[mm], 16, 64);
    num[mm] += __shfl_xor(num[mm], 32, 64);
    den[mm] += __shfl_xor(den[mm], 16, 64);
    den[mm] += __shfl_xor(den[mm], 32, 64);
  }
  if (lg == 0) {
#pragma unroll
    for (int mm = 0; mm < 2; ++mm) {
      Mrg[qg][h][mm * 16 + lr][0] = m_run[mm];
      Mrg[qg][h][mm * 16 + lr][1] = den[mm];
      Mrg[qg][h][mm * 16 + lr][2] = num[mm];
    }
  }
  __syncthreads();

  if (t < 64) {
    const int row = t & 31, qg2 = t >> 5;
    const float m0 = Mrg[qg2][0][row][0], m1 = Mrg[qg2][1][row][0];
    const float M = fmaxf(m0, m1);
    const float e0 = __expf(m0 - M), e1 = __expf(m1 - M);
    const float dt = e0 * Mrg[qg2][0][row][1] + e1 * Mrg[qg2][1][row][1];
    const float nt = e0 * Mrg[qg2][0][row][2] + e1 * Mrg[qg2][1][row][2];
    out[(size_t)b * SQ + qbase + qg2 * 32 + row] = nt / dt + Wc[256];
  }
#undef STAGE
}

// ---------------- launch ----------------
extern "C" void kernel_launch(void* const* d_in, const int* in_sizes, int n_in,
                              void* d_out, int out_size, void* d_ws, size_t ws_size,
                              hipStream_t stream) {
  const float* x     = (const float*)d_in[0];
  const float* Wqkv  = (const float*)d_in[1];
  const float* bqkv  = (const float*)d_in[2];
  const float* Wproj = (const float*)d_in[3];
  const float* bproj = (const float*)d_in[4];
  const float* Wfc   = (const float*)d_in[5];
  const float* bfc   = (const float*)d_in[6];
  float* out = (float*)d_out;

  const size_t SEG = (size_t)BQ * SQ * DQ * 2;  // 8 MB per fp16 tensor
  char* wsb = (char*)d_ws;
  short* Qb   = (short*)(wsb);
  short* Kb   = (short*)(wsb + SEG);
  char* base  = wsb + 2 * SEG;
  float* Wc   = (float*)(base);                 // 257 f
  float* u    = (float*)(base + 4096);          // 16384 f
  short* W16T = (short*)(base + 4096 + 65536);  // 768*256 fp16 = 384KB

  wcomb_kernel<<<1, 256, 0, stream>>>(Wproj, bproj, Wfc, bfc, Wc);
  wconv_kernel<<<N3, 256, 0, stream>>>(Wqkv, W16T);
  qkv_kernel<<<256, 1024, 0, stream>>>(x, W16T, bqkv, Wc, Qb, Kb, u);
  attn_kernel<<<256, 256, 0, stream>>>(Qb, Kb, u, Wc, out);
}

// Round 12
// 104.445 us; speedup vs baseline: 1.3972x; 1.3092x over previous
//
#include <hip/hip_runtime.h>
#include <hip/hip_bf16.h>

#define BQ 4
#define SQ 4096
#define DQ 256
#define N3 768
#define KBLK 64
#define NITER (SQ / KBLK)
#define KHALF (NITER / 2)

typedef __attribute__((ext_vector_type(8))) _Float16 f16x8;
typedef __attribute__((ext_vector_type(4))) float f32x4;
typedef __attribute__((ext_vector_type(4))) unsigned int u32x4;

__device__ __forceinline__ short f2h(float f) {
  _Float16 h = (_Float16)f;
  union { _Float16 h; short s; } v; v.h = h;
  return v.s;
}

__device__ __forceinline__ void gload16(const void* g, void* lds) {
  __builtin_amdgcn_global_load_lds(
      (const __attribute__((address_space(1))) unsigned int*)g,
      (__attribute__((address_space(3))) unsigned int*)lds, 16, 0, 0);
}

// ---------------- Wcomb = Wproj @ Wfc ; c0 = bproj @ Wfc + bfc ----------------
__global__ void wcomb_kernel(const float* __restrict__ Wproj,
                             const float* __restrict__ bproj,
                             const float* __restrict__ Wfc,
                             const float* __restrict__ bfc,
                             float* __restrict__ Wc) {
  __shared__ float wf[256];
  const int t = threadIdx.x;
  wf[t] = Wfc[t];
  __syncthreads();
  float acc = 0.f;
  for (int j = 0; j < 256; ++j) acc += Wproj[(size_t)t * 256 + j] * wf[j];
  Wc[t] = acc;
  if (t == 0) {
    float c = bfc[0];
    for (int j = 0; j < 256; ++j) c += bproj[j] * wf[j];
    Wc[256] = c;
  }
}

// ---------------- W16T[n][k] = fp16(Wqkv[k][n]) : 768 x 256 ----------------
__global__ void wconv_kernel(const float* __restrict__ Wqkv,
                             short* __restrict__ W16T) {
  const int n = blockIdx.x, k = threadIdx.x;
  W16T[(size_t)n * 256 + k] = f2h(Wqkv[(size_t)k * N3 + n]);
}

// ---------------- QKV projection: counted-vmcnt pipelined ----------------
__global__ __launch_bounds__(1024, 4) void qkv_kernel(
    const float* __restrict__ x, const short* __restrict__ W16T,
    const float* __restrict__ bqkv, const float* __restrict__ Wc,
    short* __restrict__ Qb, short* __restrict__ Kb, float* __restrict__ u) {
  __shared__ short xs[64][264];       // [m][k] fp16, pitch 528B
  __shared__ short ws[2][64][256];    // [buf][n][k], XOR-swizzled chunks
  __shared__ float u_red[4][4][16];
  const int t = threadIdx.x;
  const int l = t & 63, w = t >> 6;
  const int lr = l & 15, lg = l >> 4;
  const int mq = w >> 2, nq = w & 3;
  const int Mbase = blockIdx.x * 64;

#define STAGE_W(BUF, NT)                                                      \
  {                                                                           \
    _Pragma("unroll") for (int i = 0; i < 2; ++i) {                           \
      const int n = w * 4 + i * 2 + (l >> 5);                                 \
      const int gc = (l & 31) ^ (n & 7);                                      \
      gload16(W16T + (size_t)((NT)*64 + n) * 256 + gc * 8,                    \
              &ws[BUF][w * 4 + i * 2][0]);                                    \
    }                                                                         \
  }

  STAGE_W(0, 0);

  // stage x tile (plain LDS writes)
  {
    const int m = t >> 4, kc = (t & 15) * 16;
    const float* src = x + (size_t)(Mbase + m) * DQ + kc;
    short tmp[16];
#pragma unroll
    for (int i = 0; i < 16; ++i) tmp[i] = f2h(src[i]);
    *(u32x4*)&xs[m][kc] = *(u32x4*)&tmp[0];
    *(u32x4*)&xs[m][kc + 8] = *(u32x4*)&tmp[8];
  }

  // preload all bias/Wc values (keeps in-loop VM queue = staging only)
  float bias_qk[8], bias_u[4], wc_u[4];
#pragma unroll
  for (int i = 0; i < 8; ++i) bias_qk[i] = bqkv[i * 64 + nq * 16 + lr];
#pragma unroll
  for (int i = 0; i < 4; ++i) {
    bias_u[i] = bqkv[512 + i * 64 + nq * 16 + lr];
    wc_u[i] = Wc[i * 64 + nq * 16 + lr];
  }

  __syncthreads();  // drains prologue (ws buf0 + xs + preloads)

  unsigned qksto[8][2];
  float upart[4] = {0.f, 0.f, 0.f, 0.f};

#pragma unroll
  for (int nt = 0; nt < 12; ++nt) {
    const int cur = nt & 1;
    if (nt + 1 < 12) {
      STAGE_W(cur ^ 1, nt + 1);
      asm volatile("s_waitcnt vmcnt(2)" ::: "memory");
    } else {
      asm volatile("s_waitcnt vmcnt(0)" ::: "memory");
    }
    __builtin_amdgcn_s_barrier();
    __builtin_amdgcn_sched_barrier(0);

    f32x4 acc = {};
    const char* wR = (const char*)&ws[cur][nq * 16 + lr][0];
#pragma unroll
    for (int kk = 0; kk < 8; ++kk) {
      f16x8 af = *(f16x8*)&xs[mq * 16 + lr][kk * 32 + lg * 8];
      f16x8 bfr = *(const f16x8*)(wR + (((4 * kk + lg) ^ (lr & 7)) << 4));
      acc = __builtin_amdgcn_mfma_f32_16x16x32_f16(af, bfr, acc, 0, 0, 0);
    }
    if (nt < 8) {
      unsigned s0 = (unsigned short)f2h(acc[0] + bias_qk[nt]);
      unsigned s1 = (unsigned short)f2h(acc[1] + bias_qk[nt]);
      unsigned s2 = (unsigned short)f2h(acc[2] + bias_qk[nt]);
      unsigned s3 = (unsigned short)f2h(acc[3] + bias_qk[nt]);
      qksto[nt][0] = s0 | (s1 << 16);
      qksto[nt][1] = s2 | (s3 << 16);
    } else {
#pragma unroll
      for (int r = 0; r < 4; ++r) upart[r] += (acc[r] + bias_u[nt - 8]) * wc_u[nt - 8];
    }
    __builtin_amdgcn_s_barrier();
  }

  // epilogue: Q/K stores
#pragma unroll
  for (int nt = 0; nt < 8; ++nt) {
    const int col = nt * 64 + nq * 16 + lr;
#pragma unroll
    for (int r = 0; r < 4; ++r) {
      const int row = Mbase + mq * 16 + lg * 4 + r;
      const short sv = (short)((qksto[nt][r >> 1] >> ((r & 1) * 16)) & 0xFFFF);
      if (col < 256) Qb[(size_t)row * DQ + col] = sv;
      else           Kb[(size_t)row * DQ + (col - 256)] = sv;
    }
  }

  // u reduction
#pragma unroll
  for (int mask = 1; mask <= 8; mask <<= 1)
#pragma unroll
    for (int r = 0; r < 4; ++r) upart[r] += __shfl_xor(upart[r], mask, 64);
  if (lr == 0) {
#pragma unroll
    for (int r = 0; r < 4; ++r) u_red[mq][nq][lg * 4 + r] = upart[r];
  }
  __syncthreads();
  if (t < 64)
    u[Mbase + t] = u_red[t >> 4][0][t & 15] + u_red[t >> 4][1][t & 15] +
                   u_red[t >> 4][2][t & 15] + u_red[t >> 4][3][t & 15];
#undef STAGE_W
}

// ---------------- Flash attention: counted-vmcnt pipeline, key-split x2 ----
// grid 512 (2 blocks/CU), 256 thr (4 waves = 2 qg x 2 key-halves-of-tile).
// Block = 64 q-rows x 2048 keys (32 iters). K dbuf; loads stay in flight
// across barriers (vmcnt(8), never 0 in loop). u half staged to LDS
// (PER-LANE global source -- global_load_lds dest is base + lane*16).
__global__ __launch_bounds__(256, 2) void attn_kernel(
    const short* __restrict__ Qb, const short* __restrict__ Kb,
    const float* __restrict__ u, float* __restrict__ Pm,
    float* __restrict__ Pd, float* __restrict__ Pn) {
  __shared__ short Ks[2][64][256];     // [buf][key][d], XOR-swizzled chunks
  __shared__ __align__(16) float u_lds[2048];
  __shared__ float Mrg[2][2][32][3];   // [qg][h][row]{m,den,num}

  const int t = threadIdx.x;
  const int l = t & 63, w = t >> 6;
  const int lr = l & 15, lg = l >> 4;
  const int qg = w >> 1, h = w & 1;
  const int bid = blockIdx.x;
  const int b = bid & 3;
  const int half = (bid >> 2) & 1;     // bid%8 -> XCD: one (b,half) per XCD
  const int qbase = (bid >> 3) * 64;

  const short* kbase = Kb + ((size_t)b * SQ + (size_t)half * (SQ / 2)) * DQ;
  const float* ubase = u + (size_t)b * SQ + half * (SQ / 2);

#define STAGE(BUF, KB)                                                      \
  {                                                                         \
    _Pragma("unroll") for (int i = 0; i < 8; ++i) {                         \
      const int kr = w * 16 + i * 2 + (l >> 5);                             \
      const int gc = (l & 31) ^ (kr & 7);                                   \
      gload16(kbase + (size_t)((KB)*64 + kr) * DQ + gc * 8,                 \
              &Ks[BUF][w * 16 + i * 2][0]);                                 \
    }                                                                       \
  }

  STAGE(0, 0);
  // stage this (b,half)'s u slice (2048 f32): lane l loads floats 4l..4l+3
  gload16(ubase + w * 256 + (l << 2), &u_lds[w * 256]);
  gload16(ubase + (4 + w) * 256 + (l << 2), &u_lds[(4 + w) * 256]);

  // Q fragments (B-operand): wave's 32 q-rows (qg), qrow = mm*16+lr
  f16x8 qf[2][8];
#pragma unroll
  for (int mm = 0; mm < 2; ++mm) {
    const short* qptr = Qb + (size_t)(b * SQ + qbase + qg * 32 + mm * 16 + lr) * DQ;
#pragma unroll
    for (int kk = 0; kk < 8; ++kk)
      qf[mm][kk] = *(const f16x8*)(qptr + kk * 32 + lg * 8);
  }

  float m_run[2] = {-1e30f, -1e30f};
  float num[2] = {0.f, 0.f}, den[2] = {0.f, 0.f};

  __syncthreads();  // prologue drain: buf0 + u_lds + qf ready

  for (int kb = 0; kb < KHALF; ++kb) {
    const int cur = kb & 1;
    if (kb + 1 < KHALF) {
      STAGE(cur ^ 1, kb + 1);
      asm volatile("s_waitcnt vmcnt(8)" ::: "memory");  // cur-tile loads done
    } else {
      asm volatile("s_waitcnt vmcnt(0)" ::: "memory");
    }
    __builtin_amdgcn_s_barrier();          // whole tile visible; next-tile
    __builtin_amdgcn_sched_barrier(0);     // loads remain in flight

    // S^T = K Q^T on this wave's 32 keys
    f32x4 sA[2][2] = {}, sB[2][2] = {};
    __builtin_amdgcn_s_setprio(1);
#pragma unroll
    for (int kc = 0; kc < 2; ++kc) {
      const char* kR = (const char*)&Ks[cur][h * 32 + kc * 16 + lr][0];
#pragma unroll
      for (int kk = 0; kk < 4; ++kk) {
        f16x8 kf = *(const f16x8*)(kR + (((4 * kk + lg) ^ (lr & 7)) << 4));
        sA[kc][0] = __builtin_amdgcn_mfma_f32_16x16x32_f16(kf, qf[0][kk], sA[kc][0], 0, 0, 0);
        sA[kc][1] = __builtin_amdgcn_mfma_f32_16x16x32_f16(kf, qf[1][kk], sA[kc][1], 0, 0, 0);
      }
#pragma unroll
      for (int kk = 4; kk < 8; ++kk) {
        f16x8 kf = *(const f16x8*)(kR + (((4 * kk + lg) ^ (lr & 7)) << 4));
        sB[kc][0] = __builtin_amdgcn_mfma_f32_16x16x32_f16(kf, qf[0][kk], sB[kc][0], 0, 0, 0);
        sB[kc][1] = __builtin_amdgcn_mfma_f32_16x16x32_f16(kf, qf[1][kk], sB[kc][1], 0, 0, 0);
      }
    }
    __builtin_amdgcn_s_setprio(0);
    f32x4 s[2][2];
#pragma unroll
    for (int kc = 0; kc < 2; ++kc)
#pragma unroll
      for (int mm = 0; mm < 2; ++mm)
#pragma unroll
        for (int r = 0; r < 4; ++r) s[kc][mm][r] = sA[kc][mm][r] + sB[kc][mm][r];

    // defer-max online softmax; zero cross-lane ops in common path
    bool over = false;
#pragma unroll
    for (int kc = 0; kc < 2; ++kc)
#pragma unroll
      for (int mm = 0; mm < 2; ++mm)
#pragma unroll
        for (int r = 0; r < 4; ++r) over = over || (s[kc][mm][r] > m_run[mm] + 8.f);
    if (__any(over)) {
#pragma unroll
      for (int mm = 0; mm < 2; ++mm) {
        float mt = s[0][mm][0];
#pragma unroll
        for (int r = 1; r < 4; ++r) mt = fmaxf(mt, s[0][mm][r]);
#pragma unroll
        for (int r = 0; r < 4; ++r) mt = fmaxf(mt, s[1][mm][r]);
        mt = fmaxf(mt, __shfl_xor(mt, 16, 64));
        mt = fmaxf(mt, __shfl_xor(mt, 32, 64));
        const float mn = fmaxf(m_run[mm], mt);
        const float sc = __expf(m_run[mm] - mn);
        m_run[mm] = mn;
        num[mm] *= sc;
        den[mm] *= sc;
      }
    }
#pragma unroll
    for (int kc = 0; kc < 2; ++kc) {
      const f32x4 uv = *(const f32x4*)&u_lds[kb * 64 + h * 32 + kc * 16 + lg * 4];
#pragma unroll
      for (int mm = 0; mm < 2; ++mm)
#pragma unroll
        for (int r = 0; r < 4; ++r) {
          const float p = __expf(s[kc][mm][r] - m_run[mm]);  // <= e^8
          den[mm] += p;
          num[mm] += p * uv[r];
        }
    }
    __builtin_amdgcn_s_barrier();  // readers done before next STAGE overwrite
  }

  // reduce per-lane partials over the lg axis (keys)
#pragma unroll
  for (int mm = 0; mm < 2; ++mm) {
    num[mm] += __shfl_xor(num[mm], 16, 64);
    num[mm] += __shfl_xor(num[mm], 32, 64);
    den[mm] += __shfl_xor(den[mm], 16, 64);
    den[mm] += __shfl_xor(den[mm], 32, 64);
  }
  if (lg == 0) {
#pragma unroll
    for (int mm = 0; mm < 2; ++mm) {
      Mrg[qg][h][mm * 16 + lr][0] = m_run[mm];
      Mrg[qg][h][mm * 16 + lr][1] = den[mm];
      Mrg[qg][h][mm * 16 + lr][2] = num[mm];
    }
  }
  __syncthreads();

  if (t < 64) {
    const int row = t & 31, qg2 = t >> 5;
    const float m0 = Mrg[qg2][0][row][0], m1 = Mrg[qg2][1][row][0];
    const float M = fmaxf(m0, m1);
    const float e0 = __expf(m0 - M), e1 = __expf(m1 - M);
    const float dt = e0 * Mrg[qg2][0][row][1] + e1 * Mrg[qg2][1][row][1];
    const float nt = e0 * Mrg[qg2][0][row][2] + e1 * Mrg[qg2][1][row][2];
    const size_t idx = (size_t)half * (BQ * SQ) + (size_t)b * SQ + qbase + qg2 * 32 + row;
    Pm[idx] = M; Pd[idx] = dt; Pn[idx] = nt;
  }
#undef STAGE
}

// ---------------- merge the 2 key-halves ----------------
__global__ void merge_kernel(const float* __restrict__ Pm,
                             const float* __restrict__ Pd,
                             const float* __restrict__ Pn,
                             const float* __restrict__ Wc,
                             float* __restrict__ out) {
  const int gid = blockIdx.x * 256 + threadIdx.x;
  const float m0 = Pm[gid], m1 = Pm[BQ * SQ + gid];
  const float M = fmaxf(m0, m1);
  const float e0 = __expf(m0 - M), e1 = __expf(m1 - M);
  const float den = e0 * Pd[gid] + e1 * Pd[BQ * SQ + gid];
  const float num = e0 * Pn[gid] + e1 * Pn[BQ * SQ + gid];
  out[gid] = num / den + Wc[256];
}

// ---------------- launch ----------------
extern "C" void kernel_launch(void* const* d_in, const int* in_sizes, int n_in,
                              void* d_out, int out_size, void* d_ws, size_t ws_size,
                              hipStream_t stream) {
  const float* x     = (const float*)d_in[0];
  const float* Wqkv  = (const float*)d_in[1];
  const float* bqkv  = (const float*)d_in[2];
  const float* Wproj = (const float*)d_in[3];
  const float* bproj = (const float*)d_in[4];
  const float* Wfc   = (const float*)d_in[5];
  const float* bfc   = (const float*)d_in[6];
  float* out = (float*)d_out;

  const size_t SEG = (size_t)BQ * SQ * DQ * 2;  // 8 MB per fp16 tensor
  char* wsb = (char*)d_ws;
  short* Qb   = (short*)(wsb);
  short* Kb   = (short*)(wsb + SEG);
  char* base  = wsb + 2 * SEG;
  float* Wc   = (float*)(base);                          // 257 f
  float* u    = (float*)(base + 4096);                   // 16384 f
  short* W16T = (short*)(base + 4096 + 65536);           // 384 KB
  float* Pm   = (float*)(base + 4096 + 65536 + 393216);  // 32768 f
  float* Pd   = Pm + 2 * BQ * SQ;
  float* Pn   = Pd + 2 * BQ * SQ;

  wcomb_kernel<<<1, 256, 0, stream>>>(Wproj, bproj, Wfc, bfc, Wc);
  wconv_kernel<<<N3, 256, 0, stream>>>(Wqkv, W16T);
  qkv_kernel<<<256, 1024, 0, stream>>>(x, W16T, bqkv, Wc, Qb, Kb, u);
  attn_kernel<<<512, 256, 0, stream>>>(Qb, Kb, u, Pm, Pd, Pn);
  merge_kernel<<<BQ * SQ / 256, 256, 0, stream>>>(Pm, Pd, Pn, Wc, out);
}